// Round 10
// baseline (54.411 us; speedup 1.0000x reference)
//
#include <hip/hip_runtime.h>

#define CIN   64
#define HW    128
#define COUT  128
#define TH    4
#define TW    32
#define PXR   34
#define NITER (TH + 2)      // 6 iterations (two-barrier structure)
#define NTHR  512
#define HSTR  144           // bytes per histogram row (16B aligned)
#define AKSTR 136           // u16 per AK row -> 272 B (16B aligned)
#define SLOT  (PXR * HSTR)  // 4896 B per H ring slot

// LDS layout (bytes), manually packed so slot-overflow reads are well-defined:
//   [0, 19584)        Hm[4] ring slots, 34 rows x 144 B each
//   [19584, 35968)    Kt i8[128][128] (prologue only) / AK u16[48][136] (loop)
//   [35968, 36608)    SxSH int[4][40] packed (pc<<20)|ps rings
#define LDS_BYTES 36608
#define HM_OFF    0
#define KT_OFF    19584
#define SX_OFF    35968

typedef int v4i __attribute__((ext_vector_type(4)));

// lgkm-only barrier: drains LDS ops, leaves global loads/stores in flight.
__device__ __forceinline__ void wg_barrier() {
  asm volatile("s_waitcnt lgkmcnt(0)\n\ts_barrier" ::: "memory");
}

// ---------------------------------------------------------------------------
// Kernel 1: W_tab[o] = sum of quantized weights; Kt_g[o][v] i8 = K[v][o]-128
// where K[v][o] = #{w in o : qw*(128+v) > 32767}, v=0..127 (K<=255, ~7 sigma).
// ---------------------------------------------------------------------------
__global__ __launch_bounds__(128)
void build_tables(const float* __restrict__ weight, int* __restrict__ W_tab,
                  char* __restrict__ Kt_g) {
  __shared__ int qw_s[576];
  __shared__ int red_s[128];
  const int o = blockIdx.x;
  const int t = threadIdx.x;
  int partial = 0;
  for (int j = t; j < 576; j += 128) {
    float w = weight[o * 576 + j];
    int q = (int)rintf(w * 255.f);
    q = q < 0 ? 0 : (q > 255 ? 255 : q);
    qw_s[j] = q;
    partial += q;
  }
  red_s[t] = partial;
  __syncthreads();
  for (int s = 64; s > 0; s >>= 1) {
    if (t < s) red_s[t] += red_s[t + s];
    __syncthreads();
  }
  if (t == 0) W_tab[o] = red_s[0];
  const int i = 128 + t;                     // t==0 -> cnt=0 (qw*128<=32640)
  int cnt = 0;
  for (int j = 0; j < 576; ++j) cnt += (qw_s[j] * i) > 32767 ? 1 : 0;
  Kt_g[o * 128 + t] = (char)(cnt - 128);
}

// ---------------------------------------------------------------------------
// Kernel 2: prefetched quantize -> histogram (LDS atomics) -> i8 MFMA
// (K = 3 stacked rows x 128 bins) -> horizontal 3-sum + emit.
// grid = 1024 blocks 1D, XCD-remapped (b = bid&7: per XCD one batch,
// 32 h-strips x 4 w-tiles -> all w-tiles of an output line co-located).
// 36.6 KB LDS, VGPR ~56 -> 4 blocks/CU x 8 waves = 32 waves/CU (HW max).
//   iter r: stage row r | barrier | MFMA(H[r-2..r])->AK, zero slot r+1
//           (waves 6-7) | barrier | emit out-row r-2.
// ---------------------------------------------------------------------------
__global__ __launch_bounds__(NTHR, 4)
void pcilt_main(const float* __restrict__ x, const float* __restrict__ bias,
                const int* __restrict__ W_tab, const char* __restrict__ Kt_g,
                float* __restrict__ out) {
  __shared__ uint4 ldsv[LDS_BYTES / 16];
  char* ldsb = (char*)ldsv;
  unsigned char* HmB  = (unsigned char*)(ldsb + HM_OFF);
  unsigned char* KtB  = (unsigned char*)(ldsb + KT_OFF);
  unsigned short* AK  = (unsigned short*)(ldsb + KT_OFF);
  int* SxSH           = (int*)(ldsb + SX_OFF);          // [4][40]

  const int t   = (int)threadIdx.x;
  const int bid = (int)blockIdx.x;
  const int b  = bid & 7;                          // XCD owns one batch
  const int k  = bid >> 3;                         // 0..127
  const int h0 = (k >> 2) * TH;                    // 32 h-strips
  const int w0 = (k & 3) * TW;                     // 4 w-tiles

  for (int i = t; i < 4096; i += NTHR)
    ((unsigned int*)KtB)[i] = ((const unsigned int*)Kt_g)[i];
  {
    const uint4 z4 = make_uint4(0, 0, 0, 0);
    for (int i = t; i < 4 * SLOT / 16; i += NTHR) ((uint4*)HmB)[i] = z4;
    if (t < 160) SxSH[t] = 0;
  }

  const int l    = t & 15;
  const int slot = t >> 4;
  const int w    = t >> 6;
  const int kq   = (t >> 4) & 3;
  const int we   = t & 31;
  const int og   = t >> 5;

  float wf[8], bi[8];
#pragma unroll
  for (int m = 0; m < 8; ++m) {
    wf[m] = (float)W_tab[og * 8 + m];
    bi[m] = bias[og * 8 + m];
  }

  wg_barrier();

  // hoist B-fragments (Kt LDS is dead afterwards; AK reuses its space)
  v4i bfr[4][2];
  const int Mt = w >> 1, Nh = w & 1;
  if (w < 6) {
#pragma unroll
    for (int nt = 0; nt < 4; ++nt)
#pragma unroll
      for (int k64 = 0; k64 < 2; ++k64)
        bfr[nt][k64] = *(const v4i*)(KtB + (Nh * 64 + nt * 16 + l) * 128 +
                                     k64 * 64 + kq * 16);
  }

  float pf0[4], pf1[4];
  const float* xb = x + ((size_t)b * CIN + l * 4) * (HW * HW);
  const size_t cs = (size_t)HW * HW;

#define ISSUE(rn)                                                              \
  {                                                                            \
    const int iy  = h0 + (rn)-1;                                               \
    const int iyc = iy < 0 ? 0 : (iy > 127 ? 127 : iy);                        \
    const bool rok = (iy >= 0) && (iy < HW);                                   \
    int ix = w0 + slot - 1;                                                    \
    int ixc = ix < 0 ? 0 : (ix > 127 ? 127 : ix);                              \
    bool ok = rok && (ix >= 0) && (ix < HW);                                   \
    const float* xp = xb + (size_t)iyc * HW + ixc;                             \
    float v0 = xp[0], v1 = xp[cs], v2 = xp[2 * cs], v3 = xp[3 * cs];           \
    pf0[0] = ok ? v0 : 0.f; pf0[1] = ok ? v1 : 0.f;                            \
    pf0[2] = ok ? v2 : 0.f; pf0[3] = ok ? v3 : 0.f;                            \
    if (slot < 2) {                                                            \
      ix = w0 + 32 + slot - 1;                                                 \
      ixc = ix > 127 ? 127 : ix;                                               \
      ok = rok && (ix < HW);                                                   \
      const float* xq = xb + (size_t)iyc * HW + ixc;                           \
      float u0 = xq[0], u1 = xq[cs], u2 = xq[2 * cs], u3 = xq[3 * cs];         \
      pf1[0] = ok ? u0 : 0.f; pf1[1] = ok ? u1 : 0.f;                          \
      pf1[2] = ok ? u2 : 0.f; pf1[3] = ok ? u3 : 0.f;                          \
    }                                                                          \
  }

#define STAGEPX(pf, px)                                                        \
  {                                                                            \
    int q, iv0, iv1, iv2, iv3;                                                 \
    q = (int)rintf((pf)[0] * 255.f); iv0 = q < 0 ? 0 : (q > 255 ? 255 : q);    \
    q = (int)rintf((pf)[1] * 255.f); iv1 = q < 0 ? 0 : (q > 255 ? 255 : q);    \
    q = (int)rintf((pf)[2] * 255.f); iv2 = q < 0 ? 0 : (q > 255 ? 255 : q);    \
    q = (int)rintf((pf)[3] * 255.f); iv3 = q < 0 ? 0 : (q > 255 ? 255 : q);    \
    int ps = iv0 + iv1 + iv2 + iv3;                                            \
    int pc = (iv0 > 128) + (iv1 > 128) + (iv2 > 128) + (iv3 > 128);            \
    atomicAdd(&Sp[px], (pc << 20) + ps);                                       \
    unsigned char* hp = Hc + (px)*HSTR;                                        \
    if (iv0 > 128) { int v = iv0 - 128; atomicAdd((unsigned int*)(hp + ((v >> 2) << 2)), 1u << ((v & 3) * 8)); } \
    if (iv1 > 128) { int v = iv1 - 128; atomicAdd((unsigned int*)(hp + ((v >> 2) << 2)), 1u << ((v & 3) * 8)); } \
    if (iv2 > 128) { int v = iv2 - 128; atomicAdd((unsigned int*)(hp + ((v >> 2) << 2)), 1u << ((v & 3) * 8)); } \
    if (iv3 > 128) { int v = iv3 - 128; atomicAdd((unsigned int*)(hp + ((v >> 2) << 2)), 1u << ((v & 3) * 8)); } \
  }

  ISSUE(0);

  for (int r = 0; r < NITER; ++r) {
    // ---------------- stage row r from prefetched regs; issue row r+1 ------
    {
      unsigned char* Hc = HmB + (r & 3) * SLOT;
      int* Sp = &SxSH[(r & 3) * 40];
      STAGEPX(pf0, slot);
      if (slot < 2) STAGEPX(pf1, 32 + slot);
      if (r + 1 < NITER) ISSUE(r + 1);
    }
    wg_barrier();

    // ---------------- phase 2: MFMA (waves 0-5) / zero slot r+1 (6,7) ------
    if (r >= 2 && w < 6) {
      v4i acc[4];
#pragma unroll
      for (int nt = 0; nt < 4; ++nt) acc[nt] = (v4i){0, 0, 0, 0};
      const int prow = Mt * 16 + l;              // rows >=34 overflow into
#pragma unroll                                   // Kt/AK region: garbage D
      for (int st = 0; st < 3; ++st) {           // rows 34..47, never emitted
        const unsigned char* Hs = HmB + ((r - 2 + st) & 3) * SLOT +
                                  prow * HSTR + kq * 16;
#pragma unroll
        for (int k64 = 0; k64 < 2; ++k64) {
          const v4i a = *(const v4i*)(Hs + k64 * 64);
#pragma unroll
          for (int nt = 0; nt < 4; ++nt)
            acc[nt] = __builtin_amdgcn_mfma_i32_16x16x64_i8(a, bfr[nt][k64], acc[nt], 0, 0, 0);
        }
      }
      const int pbase = Mt * 16 + kq * 4;
#pragma unroll
      for (int nt = 0; nt < 4; ++nt) {
        const int o = Nh * 64 + nt * 16 + l;
#pragma unroll
        for (int rg = 0; rg < 4; ++rg)
          AK[(pbase + rg) * AKSTR + o] = (unsigned short)acc[nt][rg];
      }
    }
    if (w >= 6) {                                // zero H slot & Sx slot r+1
      const uint4 z4 = make_uint4(0, 0, 0, 0);
      uint4* Hn = (uint4*)(HmB + ((r + 1) & 3) * SLOT);
      for (int i = t - 384; i < SLOT / 16; i += 128) Hn[i] = z4;
      if (t - 384 < 40) SxSH[((r + 1) & 3) * 40 + (t - 384)] = 0;
    }
    wg_barrier();

    // ---------------- emit out-row h0 + r - 2 -------------------------------
    if (r >= 2) {
      const int h = h0 + r - 2;
      int v9 = 0;
#pragma unroll
      for (int q = 0; q < 3; ++q) {
        const int sl = (r - 2 + q) & 3;
        v9 += SxSH[sl * 40 + we] + SxSH[sl * 40 + we + 1] + SxSH[sl * 40 + we + 2];
      }
      const int sx9 = v9 & 0xFFFFF;
      const int sh9 = v9 >> 20;
      int k0 = 0, k1 = 0, k2 = 0, k3 = 0, k4 = 0, k5 = 0, k6 = 0, k7 = 0;
#pragma unroll
      for (int dx = 0; dx < 3; ++dx) {
        const uint4 p = *(const uint4*)&AK[(we + dx) * AKSTR + og * 8];
        k0 += (int)(short)(p.x & 0xffffu); k1 += (int)(short)(p.x >> 16);
        k2 += (int)(short)(p.y & 0xffffu); k3 += (int)(short)(p.y >> 16);
        k4 += (int)(short)(p.z & 0xffffu); k5 += (int)(short)(p.z >> 16);
        k6 += (int)(short)(p.w & 0xffffu); k7 += (int)(short)(p.w >> 16);
      }
      const int kc = 128 * sh9;
      const float sxf = (float)sx9;
      float* op = out + (((size_t)b * COUT + og * 8) * HW + h) * HW + (w0 + we);
      const size_t os = (size_t)HW * HW;
      op[0 * os] = sxf * wf[0] - 65536.f * (float)(k0 + kc) + bi[0];
      op[1 * os] = sxf * wf[1] - 65536.f * (float)(k1 + kc) + bi[1];
      op[2 * os] = sxf * wf[2] - 65536.f * (float)(k2 + kc) + bi[2];
      op[3 * os] = sxf * wf[3] - 65536.f * (float)(k3 + kc) + bi[3];
      op[4 * os] = sxf * wf[4] - 65536.f * (float)(k4 + kc) + bi[4];
      op[5 * os] = sxf * wf[5] - 65536.f * (float)(k5 + kc) + bi[5];
      op[6 * os] = sxf * wf[6] - 65536.f * (float)(k6 + kc) + bi[6];
      op[7 * os] = sxf * wf[7] - 65536.f * (float)(k7 + kc) + bi[7];
    }
  }
}

// ---------------------------------------------------------------------------
extern "C" void kernel_launch(void* const* d_in, const int* in_sizes, int n_in,
                              void* d_out, int out_size, void* d_ws, size_t ws_size,
                              hipStream_t stream) {
  const float* x      = (const float*)d_in[0];
  const float* weight = (const float*)d_in[1];
  const float* bias   = (const float*)d_in[2];
  float* out = (float*)d_out;

  int*  W_tab = (int*)d_ws;
  char* Kt_g  = (char*)d_ws + 512;

  build_tables<<<128, 128, 0, stream>>>(weight, W_tab, Kt_g);

  pcilt_main<<<1024, NTHR, 0, stream>>>(x, bias, W_tab, Kt_g, out);
}

// Round 11
// 43.286 us; speedup vs baseline: 1.2570x; 1.2570x over previous
//
#include <hip/hip_runtime.h>

#define CIN   64
#define HW    128
#define COUT  128
#define TH    8
#define TW    32
#define PXR   34
#define NITER (TH + 2)      // 10 iterations (R6/R9 two-barrier structure)
#define NTHR  512
#define HSTR  144           // bytes per histogram row (16B aligned)
#define AKSTR 136           // u16 per AK row -> 272 B (16B aligned)
#define SLOT  (PXR * HSTR)  // 4896 B per H ring slot

// LDS layout (bytes), manually packed:
//   [0, 19584)        Hm[4] ring slots, 34 rows x 144 B
//   [19584, 35968)    Kt i8[128][128] (prologue) / AK u16[48][136] (loop)
//   [35968, 36608)    Sx int[4][40] reduced (pc<<20)|ps per pixel
//   [36608, 39872)    Sxp int[2][34][12] quad-partials (segs 0..3 + pad)
#define HM_OFF    0
#define KT_OFF    19584
#define SX_OFF    35968
#define SXP_OFF   36608
#define LDS_BYTES 39872

typedef int v4i __attribute__((ext_vector_type(4)));

// lgkm-only barrier: drains LDS ops, leaves global loads/stores in flight.
__device__ __forceinline__ void wg_barrier() {
  asm volatile("s_waitcnt lgkmcnt(0)\n\ts_barrier" ::: "memory");
}

// sum over each aligned 4-lane quad via DPP (VALU pipe, no LDS traffic):
// quad_perm [1,0,3,2] = 0xB1 (xor1), quad_perm [2,3,0,1] = 0x4E (xor2).
__device__ __forceinline__ int quad_sum(int v) {
  v += __builtin_amdgcn_mov_dpp(v, 0xB1, 0xF, 0xF, true);
  v += __builtin_amdgcn_mov_dpp(v, 0x4E, 0xF, 0xF, true);
  return v;
}

// ---------------------------------------------------------------------------
// Kernel 1: W_tab[o] = sum of quantized weights; Kt_g[o][v] i8 = K[v][o]-128
// where K[v][o] = #{w in o : qw*(128+v) > 32767}, v=0..127 (K<=255, ~7 sigma).
// 512 threads: 4 j-parts per v, quad_sum merge (4x faster than R9's version).
// ---------------------------------------------------------------------------
__global__ __launch_bounds__(512)
void build_tables(const float* __restrict__ weight, int* __restrict__ W_tab,
                  char* __restrict__ Kt_g) {
  __shared__ int qw_s[576];
  __shared__ int red_s[144];
  const int o = blockIdx.x;
  const int t = threadIdx.x;
  for (int j = t; j < 576; j += 512) {
    float w = weight[o * 576 + j];
    int q = (int)rintf(w * 255.f);
    qw_s[j] = q < 0 ? 0 : (q > 255 ? 255 : q);
  }
  __syncthreads();
  const int v = t >> 2, part = t & 3;
  const int i = 128 + v;                     // v==0 -> cnt=0 (qw*128<=32640)
  int cnt = 0;
  const int j0 = part * 144;
  for (int j = j0; j < j0 + 144; ++j) cnt += (qw_s[j] * i) > 32767 ? 1 : 0;
  cnt = quad_sum(cnt);
  if (part == 0) Kt_g[o * 128 + v] = (char)(cnt - 128);
  if (t < 144)
    red_s[t] = qw_s[t * 4] + qw_s[t * 4 + 1] + qw_s[t * 4 + 2] + qw_s[t * 4 + 3];
  __syncthreads();
  if (t == 0) {
    int s = 0;
    for (int kk = 0; kk < 144; ++kk) s += red_s[kk];
    W_tab[o] = s;
  }
}

// ---------------------------------------------------------------------------
// Kernel 2: prefetched quantize -> histogram (LDS atomics) -> i8 MFMA
// (K = 3 stacked rows x 128 bins) -> horizontal 3-sum + emit.
// grid = 512 blocks 1D, XCD-remapped (b = bid&7). 39 KB LDS, 2 blocks/CU.
// Sx path is now LDS-atomic-free: DPP quad partials (stage, VALU) + wave-6
// micro-tree (phase 2).  Wave roles in phase 2: 0-5 MFMA, 6 Sx-tree, 7 zero.
//   iter r: stage row r | B1 | MFMA(H[r-2..r])->AK, tree Sx(r), zero H r+1
//           | B2 | emit out-row r-2.
// ---------------------------------------------------------------------------
__global__ __launch_bounds__(NTHR, 4)
void pcilt_main(const float* __restrict__ x, const float* __restrict__ bias,
                const int* __restrict__ W_tab, const char* __restrict__ Kt_g,
                float* __restrict__ out) {
  __shared__ uint4 ldsv[LDS_BYTES / 16];
  char* ldsb = (char*)ldsv;
  unsigned char* HmB  = (unsigned char*)(ldsb + HM_OFF);
  unsigned char* KtB  = (unsigned char*)(ldsb + KT_OFF);
  unsigned short* AK  = (unsigned short*)(ldsb + KT_OFF);
  int* Sx             = (int*)(ldsb + SX_OFF);     // [4][40], entries 0..33 used
  int* Sxp            = (int*)(ldsb + SXP_OFF);    // [2][34][12]

  const int t   = (int)threadIdx.x;
  const int bid = (int)blockIdx.x;
  const int b  = bid & 7;                          // XCD owns one batch
  const int k  = bid >> 3;
  const int h0 = (k >> 2) * TH;
  const int w0 = (k & 3) * TW;

  for (int i = t; i < 4096; i += NTHR)
    ((unsigned int*)KtB)[i] = ((const unsigned int*)Kt_g)[i];
  {
    const uint4 z4 = make_uint4(0, 0, 0, 0);
    for (int i = t; i < 4 * SLOT / 16; i += NTHR) ((uint4*)HmB)[i] = z4;
  }

  const int l    = t & 15;
  const int slot = t >> 4;
  const int w    = t >> 6;
  const int kq   = (t >> 4) & 3;
  const int we   = t & 31;
  const int og   = t >> 5;

  float wf[8], bi[8];
#pragma unroll
  for (int m = 0; m < 8; ++m) {
    wf[m] = (float)W_tab[og * 8 + m];
    bi[m] = bias[og * 8 + m];
  }

  wg_barrier();

  // hoist B-fragments (Kt LDS is dead afterwards; AK reuses its space)
  v4i bfr[4][2];
  const int Mt = w >> 1, Nh = w & 1;
  if (w < 6) {
#pragma unroll
    for (int nt = 0; nt < 4; ++nt)
#pragma unroll
      for (int k64 = 0; k64 < 2; ++k64)
        bfr[nt][k64] = *(const v4i*)(KtB + (Nh * 64 + nt * 16 + l) * 128 +
                                     k64 * 64 + kq * 16);
  }

  float pf0[4], pf1[4];
  const float* xb = x + ((size_t)b * CIN + l * 4) * (HW * HW);
  const size_t cs = (size_t)HW * HW;

#define ISSUE(rn)                                                              \
  {                                                                            \
    const int iy  = h0 + (rn)-1;                                               \
    const int iyc = iy < 0 ? 0 : (iy > 127 ? 127 : iy);                        \
    const bool rok = (iy >= 0) && (iy < HW);                                   \
    int ix = w0 + slot - 1;                                                    \
    int ixc = ix < 0 ? 0 : (ix > 127 ? 127 : ix);                              \
    bool ok = rok && (ix >= 0) && (ix < HW);                                   \
    const float* xp = xb + (size_t)iyc * HW + ixc;                             \
    float v0 = xp[0], v1 = xp[cs], v2 = xp[2 * cs], v3 = xp[3 * cs];           \
    pf0[0] = ok ? v0 : 0.f; pf0[1] = ok ? v1 : 0.f;                            \
    pf0[2] = ok ? v2 : 0.f; pf0[3] = ok ? v3 : 0.f;                            \
    if (slot < 2) {                                                            \
      ix = w0 + 32 + slot - 1;                                                 \
      ixc = ix > 127 ? 127 : ix;                                               \
      ok = rok && (ix < HW);                                                   \
      const float* xq = xb + (size_t)iyc * HW + ixc;                           \
      float u0 = xq[0], u1 = xq[cs], u2 = xq[2 * cs], u3 = xq[3 * cs];         \
      pf1[0] = ok ? u0 : 0.f; pf1[1] = ok ? u1 : 0.f;                          \
      pf1[2] = ok ? u2 : 0.f; pf1[3] = ok ? u3 : 0.f;                          \
    }                                                                          \
  }

// Sx: quad_sum (VALU) -> 4 partials/pixel, scatter-written conflict-free.
#define STAGEPX(pf, px)                                                        \
  {                                                                            \
    int q, iv0, iv1, iv2, iv3;                                                 \
    q = (int)rintf((pf)[0] * 255.f); iv0 = q < 0 ? 0 : (q > 255 ? 255 : q);    \
    q = (int)rintf((pf)[1] * 255.f); iv1 = q < 0 ? 0 : (q > 255 ? 255 : q);    \
    q = (int)rintf((pf)[2] * 255.f); iv2 = q < 0 ? 0 : (q > 255 ? 255 : q);    \
    q = (int)rintf((pf)[3] * 255.f); iv3 = q < 0 ? 0 : (q > 255 ? 255 : q);    \
    int pk = (((iv0 > 128) + (iv1 > 128) + (iv2 > 128) + (iv3 > 128)) << 20) + \
             (iv0 + iv1 + iv2 + iv3);                                          \
    pk = quad_sum(pk);                                                         \
    if ((l & 3) == 0) Sxp[sxpb + (px)*12 + (l >> 2)] = pk;                     \
    unsigned char* hp = Hc + (px)*HSTR;                                        \
    if (iv0 > 128) { int v = iv0 - 128; atomicAdd((unsigned int*)(hp + ((v >> 2) << 2)), 1u << ((v & 3) * 8)); } \
    if (iv1 > 128) { int v = iv1 - 128; atomicAdd((unsigned int*)(hp + ((v >> 2) << 2)), 1u << ((v & 3) * 8)); } \
    if (iv2 > 128) { int v = iv2 - 128; atomicAdd((unsigned int*)(hp + ((v >> 2) << 2)), 1u << ((v & 3) * 8)); } \
    if (iv3 > 128) { int v = iv3 - 128; atomicAdd((unsigned int*)(hp + ((v >> 2) << 2)), 1u << ((v & 3) * 8)); } \
  }

  ISSUE(0);

  for (int r = 0; r < NITER; ++r) {
    // ---------------- stage row r from prefetched regs; issue row r+1 ------
    {
      unsigned char* Hc = HmB + (r & 3) * SLOT;
      const int sxpb = (r & 1) * (34 * 12);
      STAGEPX(pf0, slot);
      if (slot < 2) STAGEPX(pf1, 32 + slot);
      if (r + 1 < NITER) ISSUE(r + 1);
    }
    wg_barrier();

    // ---------------- phase 2: MFMA (0-5) / Sx-tree (6) / zero (7) ---------
    if (r >= 2 && w < 6) {
      v4i acc[4];
#pragma unroll
      for (int nt = 0; nt < 4; ++nt) acc[nt] = (v4i){0, 0, 0, 0};
      const int prow = Mt * 16 + l;              // rows >=34 overflow into
#pragma unroll                                   // Kt/AK region: garbage D
      for (int st = 0; st < 3; ++st) {           // rows 34..47, never emitted
        const unsigned char* Hs = HmB + ((r - 2 + st) & 3) * SLOT +
                                  prow * HSTR + kq * 16;
#pragma unroll
        for (int k64 = 0; k64 < 2; ++k64) {
          const v4i a = *(const v4i*)(Hs + k64 * 64);
#pragma unroll
          for (int nt = 0; nt < 4; ++nt)
            acc[nt] = __builtin_amdgcn_mfma_i32_16x16x64_i8(a, bfr[nt][k64], acc[nt], 0, 0, 0);
        }
      }
      const int pbase = Mt * 16 + kq * 4;
#pragma unroll
      for (int nt = 0; nt < 4; ++nt) {
        const int o = Nh * 64 + nt * 16 + l;
#pragma unroll
        for (int rg = 0; rg < 4; ++rg)
          AK[(pbase + rg) * AKSTR + o] = (unsigned short)acc[nt][rg];
      }
    }
    if (w == 6) {                                // finish Sx: 4 segs -> 1
      const int L = t - 384;
      if (L < 34) {
        const v4i sq = *(const v4i*)&Sxp[(r & 1) * (34 * 12) + L * 12];
        Sx[(r & 3) * 40 + L] = sq.x + sq.y + sq.z + sq.w;
      }
    }
    if (w == 7) {                                // zero H slot r+1
      uint4* Hn = (uint4*)(HmB + ((r + 1) & 3) * SLOT);
      const uint4 z4 = make_uint4(0, 0, 0, 0);
      for (int i2 = t - 448; i2 < SLOT / 16; i2 += 64) Hn[i2] = z4;
    }
    wg_barrier();

    // ---------------- emit out-row h0 + r - 2 -------------------------------
    if (r >= 2) {
      const int h = h0 + r - 2;
      int v9 = 0;
#pragma unroll
      for (int q = 0; q < 3; ++q) {
        const int sl = (r - 2 + q) & 3;
        v9 += Sx[sl * 40 + we] + Sx[sl * 40 + we + 1] + Sx[sl * 40 + we + 2];
      }
      const int sx9 = v9 & 0xFFFFF;
      const int sh9 = v9 >> 20;
      int k0 = 0, k1 = 0, k2 = 0, k3 = 0, k4 = 0, k5 = 0, k6 = 0, k7 = 0;
#pragma unroll
      for (int dx = 0; dx < 3; ++dx) {
        const uint4 p = *(const uint4*)&AK[(we + dx) * AKSTR + og * 8];
        k0 += (int)(short)(p.x & 0xffffu); k1 += (int)(short)(p.x >> 16);
        k2 += (int)(short)(p.y & 0xffffu); k3 += (int)(short)(p.y >> 16);
        k4 += (int)(short)(p.z & 0xffffu); k5 += (int)(short)(p.z >> 16);
        k6 += (int)(short)(p.w & 0xffffu); k7 += (int)(short)(p.w >> 16);
      }
      const int kc = 128 * sh9;
      const float sxf = (float)sx9;
      float* op = out + (((size_t)b * COUT + og * 8) * HW + h) * HW + (w0 + we);
      const size_t os = (size_t)HW * HW;
      op[0 * os] = sxf * wf[0] - 65536.f * (float)(k0 + kc) + bi[0];
      op[1 * os] = sxf * wf[1] - 65536.f * (float)(k1 + kc) + bi[1];
      op[2 * os] = sxf * wf[2] - 65536.f * (float)(k2 + kc) + bi[2];
      op[3 * os] = sxf * wf[3] - 65536.f * (float)(k3 + kc) + bi[3];
      op[4 * os] = sxf * wf[4] - 65536.f * (float)(k4 + kc) + bi[4];
      op[5 * os] = sxf * wf[5] - 65536.f * (float)(k5 + kc) + bi[5];
      op[6 * os] = sxf * wf[6] - 65536.f * (float)(k6 + kc) + bi[6];
      op[7 * os] = sxf * wf[7] - 65536.f * (float)(k7 + kc) + bi[7];
    }
  }
}

// ---------------------------------------------------------------------------
extern "C" void kernel_launch(void* const* d_in, const int* in_sizes, int n_in,
                              void* d_out, int out_size, void* d_ws, size_t ws_size,
                              hipStream_t stream) {
  const float* x      = (const float*)d_in[0];
  const float* weight = (const float*)d_in[1];
  const float* bias   = (const float*)d_in[2];
  float* out = (float*)d_out;

  int*  W_tab = (int*)d_ws;
  char* Kt_g  = (char*)d_ws + 512;

  build_tables<<<128, 512, 0, stream>>>(weight, W_tab, Kt_g);

  pcilt_main<<<512, NTHR, 0, stream>>>(x, bias, W_tab, Kt_g, out);
}